// Round 2
// baseline (165.143 us; speedup 1.0000x reference)
//
#include <hip/hip_runtime.h>

#define T_N     1048576
#define BLK     256
#define S_OUT   8
#define R_BLOCK (BLK * S_OUT)        // 2048 rows per block
#define NB      (T_N / R_BLOCK)      // 512 blocks
#define WARM    64                   // 0.71^64 ~ 5e-10 carry-error decay (scan-1 contractive)
#define HALO    (WARM + 4)           // warm-up + max shift
#define SW(u)   ((u) + ((u) >> 3))   // LDS swizzle: stride 8 -> 9, gcd(9,32)=1, conflict-free

__device__ __forceinline__ float pp_step(float c, float p, float mr, float miss,
                                         float omev, float evc) {
    float last = (c > mr) ? fmaf(c - mr, miss, mr) : c;
    return fmaf(last + p, omev, -evc);
}

// Single fused kernel: scan-1 (contractive warm-up), q, scan-2 (local) + decoupled
// lookback for the inter-block linear-recurrence carry, then one coalesced store.
__global__ __launch_bounds__(BLK) void k_all(
    const float* __restrict__ x,
    const float* __restrict__ f0p, const float* __restrict__ fcp,
    const float* __restrict__ kp,  const float* __restrict__ nnp,
    const float* __restrict__ dpp, const float* __restrict__ evp,
    const float* __restrict__ evcp,const float* __restrict__ mrp,
    const float* __restrict__ missp,
    const float* __restrict__ wr1p,const float* __restrict__ wr2p,
    const float* __restrict__ wz1p,const float* __restrict__ wz2p,
    const int*   __restrict__ epp,
    float* __restrict__ out,
    unsigned int* __restrict__ ctr,           // ticket counter (memset to 0 per call)
    unsigned long long* __restrict__ pub)     // packed {flag=1 | float bits} per block
{
    __shared__ float s_prec[SW(R_BLOCK + HALO - 1) + 1];
    __shared__ float s_cG[SW(R_BLOCK + 3) + 1];
    __shared__ float s_cA[SW(R_BLOCK + 3) + 1];
    __shared__ float s_B[BLK];
    __shared__ float s_carry[BLK];
    __shared__ float s_red[BLK];
    __shared__ int   s_tile;

    const int t = threadIdx.x;
    // Ticket: tiles are acquired in scheduling order -> a block only ever spins on
    // tiles owned by blocks that are already resident => guaranteed progress.
    if (t == 0) s_tile = (int)atomicAdd(ctr, 1u);
    __syncthreads();
    const int b = s_tile;
    const int row0 = b * R_BLOCK;

    const float f0 = *f0p, fc = *fcp, kk = *kp, nn = *nnp;
    const float dp = *dpp, ev = *evp, evc = *evcp, mr = *mrp, miss = *missp;
    const float wr1 = *wr1p, wr2 = *wr2p, wz1 = *wz1p, wz2 = *wz2p;
    const int ep = *epp;
    const float omev = 1.0f - ev;
    const float cimp = 1.49f / nn;
    const float f0mfc = f0 - fc;

    const float rid = rintf(x[8]);                    // jnp.round == rint (half-even)
    const int shift = (rid == 3723.0f || rid == 870.0f) ? 1 : 4;
    const float pp0 = x[7] - x[6];                    // total_prec[0] - prec[0]

    // Stage prec column (scan-1 input) with warm-up halo.
    for (int u = t; u < R_BLOCK + HALO; u += BLK) {
        int r = row0 - HALO + u;
        s_prec[SW(u)] = (r >= 0) ? x[r * 9 + 6] : 0.0f;
    }
    // Stage per-row q coefficients for rows [row0-4, row0+R_BLOCK).
    for (int u = t; u < R_BLOCK + 4; u += BLK) {
        int r = row0 - 4 + u;
        float cg = 0.0f, ca = 0.0f;
        if (r >= 0) {
            const float* row = x + r * 9;
            float gl = row[0], imp = row[2], ar = row[3], sl = row[4], tp = row[7];
            float ft = fmaf(f0mfc, __expf(-kk * tp), fc);
            cg = gl * ar * (1.0f - ft) * 0.001f;
            ca = sqrtf(imp * ar) * cimp * sqrtf(sl);
        }
        s_cG[SW(u)] = cg;
        s_cA[SW(u)] = ca;
    }
    __syncthreads();

    // ---- scan-1 warm-up (contractive, slope <= 1-ev = 0.71 per step) ----
    const int i0 = row0 + t * S_OUT;
    const int rb = i0 - shift;
    int rr = rb - WARM; if (rr < 0) rr = 0;
    float c = (rr == 0) ? pp0 : 0.0f;
    const int rs = (rb < 0) ? 0 : rb;
    for (; rr < rs; ++rr)
        c = pp_step(c, s_prec[SW(rr - row0 + HALO)], mr, miss, omev, evc);

    // ---- q + local (zero carry-in) scan-2; hold outputs in registers ----
    float outl[S_OUT];
    float h = 0.0f;
    for (int j = 0; j < S_OUT; ++j) {
        const int i = i0 + j;
        const int r = i - shift;
        float qs = 0.0f;
        if (r >= 0) {
            float pre = fmaxf(c, 0.0f);                 // relu'd prec_pre; carry stays raw
            int ci = r - row0 + 4;
            float qg = fmaxf(pre * s_cG[SW(ci)], 0.0f);
            float di = fmaxf(fmaf(pre, 0.001f, -dp), 0.0f);
            float qi = fmaxf(s_cA[SW(ci)] * __powf(di, 5.0f / 3.0f), 0.0f);
            qs = qg + qi;
            c = pp_step(c, s_prec[SW(r - row0 + HALO)], mr, miss, omev, evc);
        }
        h = fmaf(wr1, h, wr2 * qs);     // q_shift[0]=0 keeps h=0 through i=0 (matches ref)
        outl[j] = (ep > 10) ? fmaf(wz1, h, wz2 * qs) : qs;
    }

    // thread aggregate (zero when epoch<=10 so all carry corrections vanish exactly)
    s_B[t] = (ep > 10) ? h : 0.0f;
    __syncthreads();

    const float at = powf(wr1, (float)S_OUT);       // wr1=1 -> exactly 1
    const float ab = powf(wr1, (float)R_BLOCK);

    // t0: serial intra-block carry chain (256 fmas) -> per-thread local carries +
    // block aggregate, published as one 64-bit {flag|value} release store.
    if (t == 0) {
        float acc = 0.0f;
        for (int u = 0; u < BLK; ++u) { s_carry[u] = acc; acc = fmaf(at, acc, s_B[u]); }
        unsigned long long packed =
            (1ull << 32) | (unsigned long long)__float_as_uint(acc);
        __hip_atomic_store(&pub[b], packed, __ATOMIC_RELEASE, __HIP_MEMORY_SCOPE_AGENT);
    }

    // ---- lookback: carry into block b = sum_{u<b} agg_u * ab^(b-1-u) ----
    float partial = 0.0f;
    for (int u = t; u < b; u += BLK) {
        unsigned long long v;
        for (;;) {
            v = __hip_atomic_load(&pub[u], __ATOMIC_ACQUIRE, __HIP_MEMORY_SCOPE_AGENT);
            if ((unsigned)(v >> 32) == 1u) break;   // poison 0xAAAAAAAA can't alias 1
            __builtin_amdgcn_s_sleep(1);
        }
        float agg = __uint_as_float((unsigned)v);
        partial = fmaf(agg, powf(ab, (float)(b - 1 - u)), partial);
    }
    s_red[t] = partial;
    __syncthreads();                                // also publishes s_carry from t0
    for (int off = BLK / 2; off > 0; off >>= 1) {
        if (t < off) s_red[t] += s_red[t + off];
        __syncthreads();
    }
    const float carry_block = s_red[0];

    // superposition for the linear recurrence: h_true = h_local + wr1^(j+1) * hin
    float hin = fmaf(carry_block, powf(at, (float)t), s_carry[t]);
    float p = hin;
    for (int j = 0; j < S_OUT; ++j) {
        p *= wr1;
        outl[j] = fmaf(wz1, p, outl[j]);
    }

    // coalesced store: 2 x float4 per thread, 32B-aligned
    float4 v0 = make_float4(outl[0], outl[1], outl[2], outl[3]);
    float4 v1 = make_float4(outl[4], outl[5], outl[6], outl[7]);
    float4* op = reinterpret_cast<float4*>(out + i0);
    op[0] = v0;
    op[1] = v1;
}

extern "C" void kernel_launch(void* const* d_in, const int* in_sizes, int n_in,
                              void* d_out, int out_size, void* d_ws, size_t ws_size,
                              hipStream_t stream) {
    const float* x = (const float*)d_in[0];
    float* out = (float*)d_out;
    unsigned int* ctr = (unsigned int*)d_ws;                          // 64 B
    unsigned long long* pub = (unsigned long long*)((char*)d_ws + 64); // NB*8 B

    // Zero only the ticket counter (async, graph-capture-legal). pub[] is guarded
    // by its flag word: poison 0xAAAAAAAA != 1, and stale flags from a prior replay
    // carry identical deterministic aggregates -> benign.
    hipMemsetAsync(d_ws, 0, 64, stream);

    k_all<<<NB, BLK, 0, stream>>>(x,
        (const float*)d_in[1],  (const float*)d_in[2],  (const float*)d_in[3],
        (const float*)d_in[4],  (const float*)d_in[5],  (const float*)d_in[6],
        (const float*)d_in[7],  (const float*)d_in[8],  (const float*)d_in[9],
        (const float*)d_in[10], (const float*)d_in[11], (const float*)d_in[12],
        (const float*)d_in[13], (const int*)d_in[14],
        out, ctr, pub);
}

// Round 3
// 123.096 us; speedup vs baseline: 1.3416x; 1.3416x over previous
//
#include <hip/hip_runtime.h>

#define T_N     1048576
#define BLK     256
#define S_OUT   8
#define R_BLOCK (BLK * S_OUT)        // 2048 rows per block
#define NB      (T_N / R_BLOCK)      // 512 blocks
#define NTH     (T_N / S_OUT)        // 131072 threads
#define WARM    64                   // 0.71^64 ~ 5e-10 carry-error decay (scan-1 contractive)
#define HALO    (WARM + 4)           // warm-up + max shift
#define SW(u)   ((u) + ((u) >> 3))   // LDS swizzle: stride 8 -> 9, gcd(9,32)=1, conflict-free

__device__ __forceinline__ float pp_step(float c, float p, float mr, float miss,
                                         float omev, float evc) {
    float last = (c > mr) ? fmaf(c - mr, miss, mr) : c;
    return fmaf(last + p, omev, -evc);
}

__global__ __launch_bounds__(BLK) void k_main(
    const float* __restrict__ x,
    const float* __restrict__ f0p, const float* __restrict__ fcp,
    const float* __restrict__ kp,  const float* __restrict__ nnp,
    const float* __restrict__ dpp, const float* __restrict__ evp,
    const float* __restrict__ evcp,const float* __restrict__ mrp,
    const float* __restrict__ missp,
    const float* __restrict__ wr1p,const float* __restrict__ wr2p,
    const float* __restrict__ wz1p,const float* __restrict__ wz2p,
    const int*   __restrict__ epp,
    float* __restrict__ out, float* __restrict__ Bthr, float* __restrict__ Bblk)
{
    __shared__ float s_prec[SW(R_BLOCK + HALO - 1) + 1];
    __shared__ float s_cG[SW(R_BLOCK + 3) + 1];
    __shared__ float s_cA[SW(R_BLOCK + 3) + 1];
    __shared__ float s_B[BLK];

    const int b = blockIdx.x, t = threadIdx.x;
    const int row0 = b * R_BLOCK;

    const float f0 = *f0p, fc = *fcp, kk = *kp, nn = *nnp;
    const float dp = *dpp, ev = *evp, evc = *evcp, mr = *mrp, miss = *missp;
    const float wr1 = *wr1p, wr2 = *wr2p, wz1 = *wz1p, wz2 = *wz2p;
    const int ep = *epp;
    const float omev = 1.0f - ev;
    const float cimp = 1.49f / nn;
    const float f0mfc = f0 - fc;

    const float rid = rintf(x[8]);                    // jnp.round == rint (half-even)
    const int shift = (rid == 3723.0f || rid == 870.0f) ? 1 : 4;
    const float pp0 = x[7] - x[6];                    // total_prec[0] - prec[0]

    // Stage prec column (scan-1 input) with warm-up halo. Rows are 36 B; every
    // 64 B line holds needed data -> 36 MB total fetch is the floor.
    for (int u = t; u < R_BLOCK + HALO; u += BLK) {
        int r = row0 - HALO + u;
        s_prec[SW(u)] = (r >= 0) ? x[r * 9 + 6] : 0.0f;
    }
    // Stage per-row q coefficients for rows [row0-4, row0+R_BLOCK).
    for (int u = t; u < R_BLOCK + 4; u += BLK) {
        int r = row0 - 4 + u;
        float cg = 0.0f, ca = 0.0f;
        if (r >= 0) {
            const float* row = x + r * 9;
            float gl = row[0], imp = row[2], ar = row[3], sl = row[4], tp = row[7];
            float ft = fmaf(f0mfc, __expf(-kk * tp), fc);
            cg = gl * ar * (1.0f - ft) * 0.001f;
            ca = sqrtf(imp * ar) * cimp * sqrtf(sl);
        }
        s_cG[SW(u)] = cg;
        s_cA[SW(u)] = ca;
    }
    __syncthreads();

    // ---- scan-1: per-thread warm-up (contractive, slope <= 1-ev = 0.71/step) ----
    const int i0 = row0 + t * S_OUT;
    const int rb = i0 - shift;
    int rr = rb - WARM; if (rr < 0) rr = 0;
    float c = (rr == 0) ? pp0 : 0.0f;
    const int rs = (rb < 0) ? 0 : rb;
    for (; rr < rs; ++rr)
        c = pp_step(c, s_prec[SW(rr - row0 + HALO)], mr, miss, omev, evc);

    // ---- q + local (zero carry-in) scan-2; outputs held in registers ----
    float outl[S_OUT];
    float h = 0.0f;
    for (int j = 0; j < S_OUT; ++j) {
        const int i = i0 + j;
        const int r = i - shift;
        float qs = 0.0f;
        if (r >= 0) {
            float pre = fmaxf(c, 0.0f);                 // relu'd prec_pre; carry stays raw
            int ci = r - row0 + 4;
            float qg = fmaxf(pre * s_cG[SW(ci)], 0.0f);
            float di = fmaxf(fmaf(pre, 0.001f, -dp), 0.0f);
            float qi = fmaxf(s_cA[SW(ci)] * __powf(di, 5.0f / 3.0f), 0.0f);
            qs = qg + qi;
            c = pp_step(c, s_prec[SW(r - row0 + HALO)], mr, miss, omev, evc);
        }
        h = fmaf(wr1, h, wr2 * qs);     // q_shift[0]=0 keeps h=0 through i=0 (matches ref)
        outl[j] = (ep > 10) ? fmaf(wz1, h, wz2 * qs) : qs;
    }

    // coalesced store: 2 x float4 per thread, 32B-aligned
    float4* op = reinterpret_cast<float4*>(out + i0);
    op[0] = make_float4(outl[0], outl[1], outl[2], outl[3]);
    op[1] = make_float4(outl[4], outl[5], outl[6], outl[7]);

    // thread aggregate (zero when epoch<=10 so fix-up kernel becomes a pure no-op)
    float Bv = (ep > 10) ? h : 0.0f;
    s_B[t] = Bv;
    Bthr[b * BLK + t] = Bv;
    __syncthreads();
    if (t == 0) {
        const float at = powf(wr1, (float)S_OUT);
        float acc = 0.0f;
        for (int u = 0; u < BLK; ++u) acc = fmaf(at, acc, s_B[u]);
        Bblk[b] = acc;
    }
}

// Cross-block carry propagation + correction: out[i0+j] += wz1 * wr1^(j+1) * h_in.
// No polling: barrier-separated second launch, carries computed thread-parallel.
__global__ __launch_bounds__(BLK) void k_fix(
    float* __restrict__ out,
    const float* __restrict__ Bthr, const float* __restrict__ Bblk,
    const float* __restrict__ wr1p, const float* __restrict__ wz1p)
{
    __shared__ float sBb[NB];
    __shared__ float sB[BLK];
    __shared__ float carr[BLK];
    __shared__ float sred[BLK];
    const int b = blockIdx.x, t = threadIdx.x;
    const float wr1 = *wr1p, wz1 = *wz1p;
    for (int u = t; u < NB; u += BLK) sBb[u] = Bblk[u];
    sB[t] = Bthr[b * BLK + t];
    __syncthreads();

    // carry into block b = sum_{u<b} agg_u * ab^(b-1-u) — thread-parallel + tree reduce
    const float ab = powf(wr1, (float)R_BLOCK);     // wr1=1 -> exactly 1
    const float at = powf(wr1, (float)S_OUT);
    float partial = 0.0f;
    for (int u = t; u < b; u += BLK)
        partial = fmaf(sBb[u], powf(ab, (float)(b - 1 - u)), partial);
    sred[t] = partial;
    __syncthreads();
    for (int off = BLK / 2; off > 0; off >>= 1) {
        if (t < off) sred[t] += sred[t + off];
        __syncthreads();
    }
    // per-thread carry: serial 256-fma prefix on t0 (~0.4 us, blocks in parallel)
    if (t == 0) {
        float cth = sred[0];
        for (int u = 0; u < BLK; ++u) { carr[u] = cth; cth = fmaf(at, cth, sB[u]); }
    }
    __syncthreads();

    float hin = carr[t];
    if (hin != 0.0f) {                  // epoch<=10 or true-zero carry: exact no-op
        float4* op = reinterpret_cast<float4*>(out + b * R_BLOCK + t * S_OUT);
        float4 v0 = op[0], v1 = op[1];
        float p = hin * wz1;
        p *= wr1; v0.x += p; p *= wr1; v0.y += p; p *= wr1; v0.z += p; p *= wr1; v0.w += p;
        p *= wr1; v1.x += p; p *= wr1; v1.y += p; p *= wr1; v1.z += p; p *= wr1; v1.w += p;
        op[0] = v0;
        op[1] = v1;
    }
}

extern "C" void kernel_launch(void* const* d_in, const int* in_sizes, int n_in,
                              void* d_out, int out_size, void* d_ws, size_t ws_size,
                              hipStream_t stream) {
    const float* x = (const float*)d_in[0];
    float* out  = (float*)d_out;
    float* Bthr = (float*)d_ws;            // NTH floats (512 KB)
    float* Bblk = Bthr + NTH;              // NB floats

    k_main<<<NB, BLK, 0, stream>>>(x,
        (const float*)d_in[1],  (const float*)d_in[2],  (const float*)d_in[3],
        (const float*)d_in[4],  (const float*)d_in[5],  (const float*)d_in[6],
        (const float*)d_in[7],  (const float*)d_in[8],  (const float*)d_in[9],
        (const float*)d_in[10], (const float*)d_in[11], (const float*)d_in[12],
        (const float*)d_in[13], (const int*)d_in[14],
        out, Bthr, Bblk);

    k_fix<<<NB, BLK, 0, stream>>>(out, Bthr, Bblk,
        (const float*)d_in[10], (const float*)d_in[12]);
}